// Round 6
// baseline (27.580 us; speedup 1.0000x reference)
//
#include <hip/hip_runtime.h>

// VNCMDLoss: two-stage masked multi-reduction, persistent grid, register accumulation.
//  0 recon_real  (B,T)   f32      4 arrays x 8 MiB
//  1 recon_imag  (B,T)   f32
//  2 target_real (B,T)   f32
//  3 target_imag (B,T)   f32
//  4 eIF         (B,N,T) f32      64 MiB (masked rows skipped entirely)
//  5 target_if   (B,N,T) f32      64 MiB (masked rows skipped entirely)
//  6 mode_mask   (B,N)   i32
// Output: 4 x f32: total_loss, recon_loss, if_loss, smooth_loss
//
// Lessons encoded:
//  - R1->R2: FP64 atomicAdd = contended CAS loop (2x). Per-block stores instead.
//  - R3: __threadfence+ticket fusion => per-block L2 writeback on non-coherent
//    XCD L2s => 150us. Kernel boundary IS the sync; never fence here.
//  - R4: single-WAVE finalize = latency-serialized (+7us). Finalize = 256 thr.
//  - R5: persistent 1024-block grid (one dispatch round) beat 2560 blocks.
//  - R6 (this): ONE block-reduce per block instead of one per unit. Per-unit
//    LDS reduce + 2 syncthreads + store drained the memory pipe at every unit
//    boundary; register accumulation lets consecutive units' loads overlap.

namespace {
constexpr int    kB = 8;
constexpr int    kN = 8;
constexpr int    kT = 262144;
constexpr long long kBT  = (long long)kB * kT;        // 2,097,152
constexpr long long kBNT = (long long)kB * kN * kT;   // 16,777,216

constexpr int THREADS     = 256;
constexpr int GRID        = 1024;   // 4096 waves = 4/SIMD, all resident at t=0
constexpr int SEGS        = 32;     // segments per (b,n) row; 2048 IF units

constexpr double LAMBDA_IF     = 0.5;
constexpr double LAMBDA_SMOOTH = 0.1;
}

__device__ __forceinline__ float sq(float x) { return x * x; }

// recon unit u in [0,512): strided float4 over the 4 recon/target arrays.
__device__ __forceinline__ void recon_accum(int u, int tid,
                                            const float4* __restrict__ rr4,
                                            const float4* __restrict__ tr4,
                                            const float4* __restrict__ ri4,
                                            const float4* __restrict__ ti4,
                                            float& a0, float& a1) {
    constexpr int STRIDE = 512 * THREADS;     // 131072 float4 per array
    const int base = u * THREADS + tid;
    const int v0 = base, v1 = base + STRIDE, v2 = base + 2 * STRIDE, v3 = base + 3 * STRIDE;
    float4 x0 = rr4[v0], x1 = rr4[v1], x2 = rr4[v2], x3 = rr4[v3];
    float4 y0 = tr4[v0], y1 = tr4[v1], y2 = tr4[v2], y3 = tr4[v3];
    float4 u0 = ri4[v0], u1 = ri4[v1], u2 = ri4[v2], u3 = ri4[v3];
    float4 w0 = ti4[v0], w1 = ti4[v1], w2 = ti4[v2], w3 = ti4[v3];
    a0 += sq(x0.x - y0.x) + sq(x0.y - y0.y) + sq(x0.z - y0.z) + sq(x0.w - y0.w)
        + sq(x1.x - y1.x) + sq(x1.y - y1.y) + sq(x1.z - y1.z) + sq(x1.w - y1.w)
        + sq(x2.x - y2.x) + sq(x2.y - y2.y) + sq(x2.z - y2.z) + sq(x2.w - y2.w)
        + sq(x3.x - y3.x) + sq(x3.y - y3.y) + sq(x3.z - y3.z) + sq(x3.w - y3.w);
    a1 += sq(u0.x - w0.x) + sq(u0.y - w0.y) + sq(u0.z - w0.z) + sq(u0.w - w0.w)
        + sq(u1.x - w1.x) + sq(u1.y - w1.y) + sq(u1.z - w1.z) + sq(u1.w - w1.w)
        + sq(u2.x - w2.x) + sq(u2.y - w2.y) + sq(u2.z - w2.z) + sq(u2.w - w2.w)
        + sq(u3.x - w3.x) + sq(u3.y - w3.y) + sq(u3.z - w3.z) + sq(u3.w - w3.w);
}

// IF unit iu in [0,2048): (row, segment); masked rows contribute nothing.
__device__ __forceinline__ void if_accum(int iu, int tid,
                                         const float* __restrict__ eIF,
                                         const float* __restrict__ tIF,
                                         const int* __restrict__ smask,
                                         float& a2, float& a3) {
    const int row = iu >> 5;              // / SEGS
    const int seg = iu & (SEGS - 1);
    if (smask[row] != 1) return;          // block-uniform branch

    const float4* e4 = (const float4*)(eIF + (size_t)row * kT);
    const float4* t4 = (const float4*)(tIF + (size_t)row * kT);
    constexpr int VPR = kT / 4;           // 65536 vectors per row
    constexpr int VPS = 2048;             // vectors per segment (8 per thread)
    const int v0 = seg * VPS + tid;
    const bool lane63 = (tid & 63) == 63;

    #pragma unroll
    for (int h = 0; h < 2; ++h) {
        const int b0 = v0 + (4 * h) * THREADS;
        const int b1 = b0 + THREADS, b2 = b0 + 2 * THREADS, b3 = b0 + 3 * THREADS;
        float4 e0 = e4[b0], e1 = e4[b1], e2 = e4[b2], e3 = e4[b3];
        float4 q0 = t4[b0], q1 = t4[b1], q2 = t4[b2], q3 = t4[b3];
        float n0 = 0.f, n1 = 0.f, n2 = 0.f, n3 = 0.f;
        if (lane63) {                     // wave-edge boundary scalars (L1/L2 hits)
            n0 = (b0 + 1 < VPR) ? e4[b0 + 1].x : e0.w;
            n1 = (b1 + 1 < VPR) ? e4[b1 + 1].x : e1.w;
            n2 = (b2 + 1 < VPR) ? e4[b2 + 1].x : e2.w;
            n3 = (b3 + 1 < VPR) ? e4[b3 + 1].x : e3.w;
        }
        a2 += sq(e0.x - q0.x) + sq(e0.y - q0.y) + sq(e0.z - q0.z) + sq(e0.w - q0.w)
            + sq(e1.x - q1.x) + sq(e1.y - q1.y) + sq(e1.z - q1.z) + sq(e1.w - q1.w)
            + sq(e2.x - q2.x) + sq(e2.y - q2.y) + sq(e2.z - q2.z) + sq(e2.w - q2.w)
            + sq(e3.x - q3.x) + sq(e3.y - q3.y) + sq(e3.z - q3.z) + sq(e3.w - q3.w);
        a3 += sq(e0.y - e0.x) + sq(e0.z - e0.y) + sq(e0.w - e0.z)
            + sq(e1.y - e1.x) + sq(e1.z - e1.y) + sq(e1.w - e1.z)
            + sq(e2.y - e2.x) + sq(e2.z - e2.y) + sq(e2.w - e2.z)
            + sq(e3.y - e3.x) + sq(e3.z - e3.y) + sq(e3.w - e3.z);
        float s0 = __shfl_down(e0.x, 1, 64);
        float s1 = __shfl_down(e1.x, 1, 64);
        float s2 = __shfl_down(e2.x, 1, 64);
        float s3 = __shfl_down(e3.x, 1, 64);
        if (lane63) { s0 = n0; s1 = n1; s2 = n2; s3 = n3; }
        a3 += sq(s0 - e0.w) + sq(s1 - e1.w) + sq(s2 - e2.w) + sq(s3 - e3.w);
    }
}

__global__ __launch_bounds__(THREADS, 4)
void vncmd_main_kernel(const float* __restrict__ rr, const float* __restrict__ ri,
                       const float* __restrict__ tr, const float* __restrict__ ti,
                       const float* __restrict__ eIF, const float* __restrict__ tIF,
                       const int* __restrict__ mask, double* __restrict__ ws) {
    const int tid = threadIdx.x;
    const int bid = blockIdx.x;

    __shared__ int smask[kB * kN];
    if (tid < kB * kN) smask[tid] = mask[tid];
    __syncthreads();

    const float4* rr4 = (const float4*)rr;
    const float4* tr4 = (const float4*)tr;
    const float4* ri4 = (const float4*)ri;
    const float4* ti4 = (const float4*)ti;

    float a0 = 0.f, a1 = 0.f, a2 = 0.f, a3 = 0.f;
    if (bid < 512) {
        // recon(bid) + IF(bid+512) + IF(bid+1536)
        recon_accum(bid, tid, rr4, tr4, ri4, ti4, a0, a1);
        if_accum(bid + 512,  tid, eIF, tIF, smask, a2, a3);
        if_accum(bid + 1536, tid, eIF, tIF, smask, a2, a3);
    } else {
        // IF(bid-512) + IF(bid+512)
        if_accum(bid - 512, tid, eIF, tIF, smask, a2, a3);
        if_accum(bid + 512, tid, eIF, tIF, smask, a2, a3);
    }

    // ---- single block reduction: 4 partials -> 4 doubles at ws[4*bid] ----
    double d0 = (double)a0, d1 = (double)a1, d2 = (double)a2, d3 = (double)a3;
    #pragma unroll
    for (int o = 32; o > 0; o >>= 1) {
        d0 += __shfl_down(d0, o, 64);
        d1 += __shfl_down(d1, o, 64);
        d2 += __shfl_down(d2, o, 64);
        d3 += __shfl_down(d3, o, 64);
    }
    __shared__ double lds[4][4];
    const int lane = tid & 63;
    const int wid  = tid >> 6;
    if (lane == 0) { lds[wid][0] = d0; lds[wid][1] = d1; lds[wid][2] = d2; lds[wid][3] = d3; }
    __syncthreads();
    if (tid == 0) {
        double* dst = ws + 4 * bid;
        dst[0] = lds[0][0] + lds[1][0] + lds[2][0] + lds[3][0];
        dst[1] = lds[0][1] + lds[1][1] + lds[2][1] + lds[3][1];
        dst[2] = lds[0][2] + lds[1][2] + lds[2][2] + lds[3][2];
        dst[3] = lds[0][3] + lds[1][3] + lds[2][3] + lds[3][3];
    }
}

// 256-thread finalize: reduce 1024 x 4 doubles (32 KB), write the 4 outputs.
__global__ __launch_bounds__(THREADS)
void finalize_kernel(const double* __restrict__ ws,
                     const int* __restrict__ mask,
                     float* __restrict__ out) {
    const int tid = threadIdx.x;
    const double2* w2 = (const double2*)ws;
    double s0 = 0.0, s1 = 0.0, s2 = 0.0, s3 = 0.0;
    #pragma unroll
    for (int k = 0; k < GRID / THREADS; ++k) {
        const int b = k * THREADS + tid;
        double2 p = w2[2 * b], q = w2[2 * b + 1];
        s0 += p.x; s1 += p.y; s2 += q.x; s3 += q.y;
    }
    #pragma unroll
    for (int o = 32; o > 0; o >>= 1) {
        s0 += __shfl_down(s0, o, 64);
        s1 += __shfl_down(s1, o, 64);
        s2 += __shfl_down(s2, o, 64);
        s3 += __shfl_down(s3, o, 64);
    }
    __shared__ double lds[4][4];
    const int lane = tid & 63;
    const int wid  = tid >> 6;
    if (lane == 0) { lds[wid][0] = s0; lds[wid][1] = s1; lds[wid][2] = s2; lds[wid][3] = s3; }
    __syncthreads();
    if (tid == 0) {
        double t0 = lds[0][0] + lds[1][0] + lds[2][0] + lds[3][0];
        double t1 = lds[0][1] + lds[1][1] + lds[2][1] + lds[3][1];
        double t2 = lds[0][2] + lds[1][2] + lds[2][2] + lds[3][2];
        double t3 = lds[0][3] + lds[1][3] + lds[2][3] + lds[3][3];
        int c = 0;
        #pragma unroll
        for (int i = 0; i < kB * kN; ++i) c += (mask[i] == 1);
        double count = (double)c;
        double recon = t0 / (double)kBT + t1 / (double)kBT;
        double ifl   = t2 / (double)kBNT;
        double denom = (count > 1.0 ? count : 1.0) * (double)(kT - 1);
        double smooth = t3 / denom;
        double total = recon + LAMBDA_IF * ifl + (count > 0.0 ? LAMBDA_SMOOTH * smooth : 0.0);
        out[0] = (float)total;
        out[1] = (float)recon;
        out[2] = (float)ifl;
        out[3] = (float)smooth;
    }
}

extern "C" void kernel_launch(void* const* d_in, const int* in_sizes, int n_in,
                              void* d_out, int out_size, void* d_ws, size_t ws_size,
                              hipStream_t stream) {
    const float* rr  = (const float*)d_in[0];
    const float* ri  = (const float*)d_in[1];
    const float* tr  = (const float*)d_in[2];
    const float* ti  = (const float*)d_in[3];
    const float* eIF = (const float*)d_in[4];
    const float* tIF = (const float*)d_in[5];
    const int*   msk = (const int*)d_in[6];
    float* out = (float*)d_out;
    double* ws = (double*)d_ws;

    vncmd_main_kernel<<<GRID, THREADS, 0, stream>>>(
        rr, ri, tr, ti, eIF, tIF, msk, ws);
    finalize_kernel<<<1, THREADS, 0, stream>>>(ws, msk, out);
}

// Round 7
// 24.815 us; speedup vs baseline: 1.1114x; 1.1114x over previous
//
#include <hip/hip_runtime.h>

// VNCMDLoss: two-stage masked multi-reduction. Full-slot grid, lean registers.
//  0 recon_real  (B,T)   f32      4 arrays x 8 MiB
//  1 recon_imag  (B,T)   f32
//  2 target_real (B,T)   f32
//  3 target_imag (B,T)   f32
//  4 eIF         (B,N,T) f32      64 MiB (masked rows skipped entirely)
//  5 target_if   (B,N,T) f32      64 MiB (masked rows skipped entirely)
//  6 mode_mask   (B,N)   i32
// Output: 4 x f32: total_loss, recon_loss, if_loss, smooth_loss
//
// Lessons encoded:
//  - R1->R2: FP64 atomicAdd = contended CAS loop (2x). Per-block stores.
//  - R3: __threadfence+ticket fusion => L2 writeback per block on non-coherent
//    XCD L2s => 6x slower. Kernel boundary IS the sync; never fence.
//  - R4: single-WAVE finalize = latency-serialized. Finalize = 256 threads.
//  - R6: 16-deep load batches + __launch_bounds__ cap => scratch spills
//    (WRITE_SIZE 160KB -> 6.2MB) on the critical path. Batch <= 8 loads.
//  - R6 counters: runtime invariant to HBM vs L3 residency => latency/TLP
//    bound, not BW bound. Fix = occupancy: 2048 blocks x 4 waves = ALL 8192
//    wave slots resident in one dispatch round; perfectly balanced work:
//    every block = recon(b) + IF(b) + IF(b+2048) = 20 loads/thread.

namespace {
constexpr int    kB = 8;
constexpr int    kN = 8;
constexpr int    kT = 262144;
constexpr long long kBT  = (long long)kB * kT;        // 2,097,152
constexpr long long kBNT = (long long)kB * kN * kT;   // 16,777,216

constexpr int THREADS     = 256;
constexpr int GRID        = 2048;   // 8 blocks/CU, 8192 waves = every slot
constexpr int RECON_UNITS = 2048;   // 1 float4/thread/array per unit
constexpr int IF_SEGS     = 64;     // per row; 1024 vectors (4/thread) per unit
constexpr int IF_UNITS    = kB * kN * IF_SEGS;   // 4096

constexpr double LAMBDA_IF     = 0.5;
constexpr double LAMBDA_SMOOTH = 0.1;
}

__device__ __forceinline__ float sq(float x) { return x * x; }

// recon unit u in [0,2048): one float4 per thread per array (4 loads).
__device__ __forceinline__ void recon_accum(int u, int tid,
                                            const float4* __restrict__ rr4,
                                            const float4* __restrict__ tr4,
                                            const float4* __restrict__ ri4,
                                            const float4* __restrict__ ti4,
                                            float& a0, float& a1) {
    const int v = u * THREADS + tid;          // [0, 524288)
    float4 x = rr4[v], y = tr4[v];
    float4 m = ri4[v], w = ti4[v];
    a0 += sq(x.x - y.x) + sq(x.y - y.y) + sq(x.z - y.z) + sq(x.w - y.w);
    a1 += sq(m.x - w.x) + sq(m.y - w.y) + sq(m.z - w.z) + sq(m.w - w.w);
}

// IF unit iu in [0,4096): (row, seg); 1024 vectors; 8 loads per thread.
__device__ __forceinline__ void if_accum(int iu, int tid,
                                         const float* __restrict__ eIF,
                                         const float* __restrict__ tIF,
                                         const int* __restrict__ smask,
                                         float& a2, float& a3) {
    const int row = iu >> 6;                  // / IF_SEGS
    const int seg = iu & (IF_SEGS - 1);
    if (smask[row] != 1) return;              // block-uniform; masked row = 0

    const float4* e4 = (const float4*)(eIF + (size_t)row * kT);
    const float4* t4 = (const float4*)(tIF + (size_t)row * kT);
    constexpr int VPR = kT / 4;               // 65536 vectors per row
    const int base = seg * 1024 + tid;
    const int b0 = base, b1 = base + 256, b2 = base + 512, b3 = base + 768;
    const bool lane63 = (tid & 63) == 63;

    // 8 loads issued back-to-back (32 data VGPRs)
    float4 e0 = e4[b0], e1 = e4[b1], e2 = e4[b2], e3 = e4[b3];
    float4 q0 = t4[b0], q1 = t4[b1], q2 = t4[b2], q3 = t4[b3];
    float n0 = 0.f, n1 = 0.f, n2 = 0.f, n3 = 0.f;
    if (lane63) {                             // wave-edge boundary scalars
        n0 = e4[b0 + 1].x;                    // b0+1..b2+1 < VPR always
        n1 = e4[b1 + 1].x;
        n2 = e4[b2 + 1].x;
        n3 = (b3 + 1 < VPR) ? e4[b3 + 1].x : e3.w;   // row end -> zero term
    }
    a2 += sq(e0.x - q0.x) + sq(e0.y - q0.y) + sq(e0.z - q0.z) + sq(e0.w - q0.w)
        + sq(e1.x - q1.x) + sq(e1.y - q1.y) + sq(e1.z - q1.z) + sq(e1.w - q1.w)
        + sq(e2.x - q2.x) + sq(e2.y - q2.y) + sq(e2.z - q2.z) + sq(e2.w - q2.w)
        + sq(e3.x - q3.x) + sq(e3.y - q3.y) + sq(e3.z - q3.z) + sq(e3.w - q3.w);
    a3 += sq(e0.y - e0.x) + sq(e0.z - e0.y) + sq(e0.w - e0.z)
        + sq(e1.y - e1.x) + sq(e1.z - e1.y) + sq(e1.w - e1.z)
        + sq(e2.y - e2.x) + sq(e2.z - e2.y) + sq(e2.w - e2.z)
        + sq(e3.y - e3.x) + sq(e3.z - e3.y) + sq(e3.w - e3.z);
    float s0 = __shfl_down(e0.x, 1, 64);
    float s1 = __shfl_down(e1.x, 1, 64);
    float s2 = __shfl_down(e2.x, 1, 64);
    float s3 = __shfl_down(e3.x, 1, 64);
    if (lane63) { s0 = n0; s1 = n1; s2 = n2; s3 = n3; }
    a3 += sq(s0 - e0.w) + sq(s1 - e1.w) + sq(s2 - e2.w) + sq(s3 - e3.w);
}

__global__ __launch_bounds__(THREADS, 8)
void vncmd_main_kernel(const float* __restrict__ rr, const float* __restrict__ ri,
                       const float* __restrict__ tr, const float* __restrict__ ti,
                       const float* __restrict__ eIF, const float* __restrict__ tIF,
                       const int* __restrict__ mask, double* __restrict__ ws) {
    const int tid = threadIdx.x;
    const int bid = blockIdx.x;

    __shared__ int smask[kB * kN];
    if (tid < kB * kN) smask[tid] = mask[tid];
    __syncthreads();

    float a0 = 0.f, a1 = 0.f, a2 = 0.f, a3 = 0.f;
    recon_accum(bid, tid, (const float4*)rr, (const float4*)tr,
                (const float4*)ri, (const float4*)ti, a0, a1);
    if_accum(bid,        tid, eIF, tIF, smask, a2, a3);
    if_accum(bid + 2048, tid, eIF, tIF, smask, a2, a3);

    // ---- single block reduction: 4 partials -> 4 doubles at ws[4*bid] ----
    double d0 = (double)a0, d1 = (double)a1, d2 = (double)a2, d3 = (double)a3;
    #pragma unroll
    for (int o = 32; o > 0; o >>= 1) {
        d0 += __shfl_down(d0, o, 64);
        d1 += __shfl_down(d1, o, 64);
        d2 += __shfl_down(d2, o, 64);
        d3 += __shfl_down(d3, o, 64);
    }
    __shared__ double lds[4][4];
    const int lane = tid & 63;
    const int wid  = tid >> 6;
    if (lane == 0) { lds[wid][0] = d0; lds[wid][1] = d1; lds[wid][2] = d2; lds[wid][3] = d3; }
    __syncthreads();
    if (tid == 0) {
        double* dst = ws + 4 * bid;
        dst[0] = lds[0][0] + lds[1][0] + lds[2][0] + lds[3][0];
        dst[1] = lds[0][1] + lds[1][1] + lds[2][1] + lds[3][1];
        dst[2] = lds[0][2] + lds[1][2] + lds[2][2] + lds[3][2];
        dst[3] = lds[0][3] + lds[1][3] + lds[2][3] + lds[3][3];
    }
}

// 256-thread finalize: reduce 2048 x 4 doubles (64 KB), write the 4 outputs.
__global__ __launch_bounds__(THREADS)
void finalize_kernel(const double* __restrict__ ws,
                     const int* __restrict__ mask,
                     float* __restrict__ out) {
    const int tid = threadIdx.x;
    const double2* w2 = (const double2*)ws;
    double s0 = 0.0, s1 = 0.0, s2 = 0.0, s3 = 0.0;
    #pragma unroll
    for (int k = 0; k < GRID / THREADS; ++k) {
        const int b = k * THREADS + tid;
        double2 p = w2[2 * b], q = w2[2 * b + 1];
        s0 += p.x; s1 += p.y; s2 += q.x; s3 += q.y;
    }
    #pragma unroll
    for (int o = 32; o > 0; o >>= 1) {
        s0 += __shfl_down(s0, o, 64);
        s1 += __shfl_down(s1, o, 64);
        s2 += __shfl_down(s2, o, 64);
        s3 += __shfl_down(s3, o, 64);
    }
    __shared__ double lds[4][4];
    const int lane = tid & 63;
    const int wid  = tid >> 6;
    if (lane == 0) { lds[wid][0] = s0; lds[wid][1] = s1; lds[wid][2] = s2; lds[wid][3] = s3; }
    __syncthreads();
    if (tid == 0) {
        double t0 = lds[0][0] + lds[1][0] + lds[2][0] + lds[3][0];
        double t1 = lds[0][1] + lds[1][1] + lds[2][1] + lds[3][1];
        double t2 = lds[0][2] + lds[1][2] + lds[2][2] + lds[3][2];
        double t3 = lds[0][3] + lds[1][3] + lds[2][3] + lds[3][3];
        int c = 0;
        #pragma unroll
        for (int i = 0; i < kB * kN; ++i) c += (mask[i] == 1);
        double count = (double)c;
        double recon = t0 / (double)kBT + t1 / (double)kBT;
        double ifl   = t2 / (double)kBNT;
        double denom = (count > 1.0 ? count : 1.0) * (double)(kT - 1);
        double smooth = t3 / denom;
        double total = recon + LAMBDA_IF * ifl + (count > 0.0 ? LAMBDA_SMOOTH * smooth : 0.0);
        out[0] = (float)total;
        out[1] = (float)recon;
        out[2] = (float)ifl;
        out[3] = (float)smooth;
    }
}

extern "C" void kernel_launch(void* const* d_in, const int* in_sizes, int n_in,
                              void* d_out, int out_size, void* d_ws, size_t ws_size,
                              hipStream_t stream) {
    const float* rr  = (const float*)d_in[0];
    const float* ri  = (const float*)d_in[1];
    const float* tr  = (const float*)d_in[2];
    const float* ti  = (const float*)d_in[3];
    const float* eIF = (const float*)d_in[4];
    const float* tIF = (const float*)d_in[5];
    const int*   msk = (const int*)d_in[6];
    float* out = (float*)d_out;
    double* ws = (double*)d_ws;

    vncmd_main_kernel<<<GRID, THREADS, 0, stream>>>(
        rr, ri, tr, ti, eIF, tIF, msk, ws);
    finalize_kernel<<<1, THREADS, 0, stream>>>(ws, msk, out);
}